// Round 13
// baseline (214.634 us; speedup 1.0000x reference)
//
#include <hip/hip_runtime.h>
#include <stdint.h>

// VectorQuantizer: x[32,64,64,64] NCHW fp32, W[512,64] fp32.
// argmin_k ||x - w_k||^2 ; out = W[argmin] in NCHW.
//
// v13: code-slice ownership. 512-thr blocks (8 waves), 256 tokens/block.
// Wave w holds the A-fragments of codes w*64..w*64+63 (4 tiles) in 32 VGPRs;
// tokens staged once in swizzled bf16 LDS and streamed (2 ds_read_b128 +
// 8 MFMA per 16-token group). Cross-wave merge via LDS: per-wave maxes ->
// per-token threshold (margin 2^-7*||x||*Wmax+0.02) -> candidate masks ->
// per-token resolution (singleton exact / serial fp64 refine).

typedef short short8 __attribute__((ext_vector_type(8)));
typedef float f32x4 __attribute__((ext_vector_type(4)));
typedef unsigned u32x4 __attribute__((ext_vector_type(4)));

#define HW_ 4096

__device__ __forceinline__ unsigned short f2bf(float f) {
    unsigned u = __float_as_uint(f);
    u += 0x7fff + ((u >> 16) & 1);   // RNE to bf16
    return (unsigned short)(u >> 16);
}

// Image: ushort idx(k,d) = (d>>3)*4096 + k*8 + (d&7)   [8 octet-planes]
__global__ __launch_bounds__(64) void vq_prep(const float* __restrict__ W,
                                              unsigned short* __restrict__ Wb,
                                              float* __restrict__ nh,
                                              int* __restrict__ wmax2i) {
    const int k = blockIdx.x, l = threadIdx.x;
    float v = W[k * 64 + l];
    Wb[(l >> 3) * 4096 + k * 8 + (l & 7)] = f2bf(v);
    float s = v * v;
    #pragma unroll
    for (int off = 1; off < 64; off <<= 1) s += __shfl_xor(s, off);
    if (l == 0) {
        nh[k] = -0.5f * s;
        atomicMax(wmax2i, __float_as_int(s));
    }
}

__global__ __launch_bounds__(512, 4) void vq_main(const float* __restrict__ x,
                                                  const float* __restrict__ W,
                                                  const unsigned short* __restrict__ Wb,
                                                  const float* __restrict__ nh,
                                                  const int* __restrict__ wmax2i,
                                                  float* __restrict__ out) {
    __shared__ unsigned short xb[256 * 64];        // 32 KiB swizzled bf16 tokens
    __shared__ float wavemax[8][256];              // 8 KiB
    __shared__ unsigned long long cmask[8][256];   // 16 KiB
    __shared__ float xsqpart[2][256];              // 2 KiB
    __shared__ float thrArr[256];                  // 1 KiB
    __shared__ int bkArr[256];                     // 1 KiB

    const int tid = threadIdx.x;
    const int bid = blockIdx.x;
    const int b = bid >> 4;                 // batch 0..31
    const int p0 = (bid & 15) << 8;         // 256-token spatial base
    const int l = tid & 63;
    const int wv = tid >> 6;                // wave 0..7 owns codes wv*64..+63

    // ---- this wave's A-fragments (4 tiles) + nh C-inits, in registers ----
    short8 a0_0, a0_1, a0_2, a0_3, a1_0, a1_1, a1_2, a1_3;
    f32x4 nhv0, nhv1, nhv2, nhv3;
    {
        const unsigned short* Ap = Wb + (l >> 4) * 4096 + ((wv * 4) * 16 + (l & 15)) * 8;
        const unsigned short* Aq = Ap + 4 * 4096;
        a0_0 = *(const short8*)(Ap);        a1_0 = *(const short8*)(Aq);
        a0_1 = *(const short8*)(Ap + 128);  a1_1 = *(const short8*)(Aq + 128);
        a0_2 = *(const short8*)(Ap + 256);  a1_2 = *(const short8*)(Aq + 256);
        a0_3 = *(const short8*)(Ap + 384);  a1_3 = *(const short8*)(Aq + 384);
        const float* np = nh + (wv * 4) * 16 + (l >> 4) * 4;
        nhv0 = *(const f32x4*)(np);
        nhv1 = *(const f32x4*)(np + 16);
        nhv2 = *(const f32x4*)(np + 32);
        nhv3 = *(const f32x4*)(np + 48);
    }

    // ---- stage 256 tokens into swizzled LDS; xsq partials ----
    {
        const int tok = tid & 255;
        const int half = tid >> 8;
        const float* xp = x + (size_t)(b * 64 + half * 32) * HW_ + p0 + tok;
        float xsq = 0.f;
        #pragma unroll
        for (int c4 = 0; c4 < 4; ++c4) {
            float v[8];
            #pragma unroll
            for (int e = 0; e < 8; ++e) {
                v[e] = xp[(size_t)(c4 * 8 + e) * HW_];
                xsq += v[e] * v[e];
            }
            u32x4 pk;
            #pragma unroll
            for (int q = 0; q < 4; ++q)
                pk[q] = (unsigned)f2bf(v[2 * q]) | ((unsigned)f2bf(v[2 * q + 1]) << 16);
            const int slot = (half * 4 + c4) ^ (tok & 7);
            *(u32x4*)((char*)xb + tok * 128 + slot * 16) = pk;
        }
        xsqpart[half][tok] = xsq;
    }
    const float wm2 = __int_as_float(*wmax2i);
    __syncthreads();

    // lane-constant swizzled byte offsets (tok&7 == l&7 within every group)
    const int off0 = (((l >> 4)    ) ^ (l & 7)) * 16;
    const int off1 = (((l >> 4) + 4) ^ (l & 7)) * 16;
    const char* xbB = (const char*)xb + (l & 15) * 128;

    #define SCORES(G, A0, A1, A2, A3)                                              \
        short8 b0 = *(const short8*)(xbB + (G) * 2048 + off0);                      \
        short8 b1 = *(const short8*)(xbB + (G) * 2048 + off1);                      \
        f32x4 A0 = nhv0, A1 = nhv1, A2 = nhv2, A3 = nhv3;                           \
        A0 = __builtin_amdgcn_mfma_f32_16x16x32_bf16(a0_0, b0, A0, 0, 0, 0);        \
        A1 = __builtin_amdgcn_mfma_f32_16x16x32_bf16(a0_1, b0, A1, 0, 0, 0);        \
        A2 = __builtin_amdgcn_mfma_f32_16x16x32_bf16(a0_2, b0, A2, 0, 0, 0);        \
        A3 = __builtin_amdgcn_mfma_f32_16x16x32_bf16(a0_3, b0, A3, 0, 0, 0);        \
        A0 = __builtin_amdgcn_mfma_f32_16x16x32_bf16(a1_0, b1, A0, 0, 0, 0);        \
        A1 = __builtin_amdgcn_mfma_f32_16x16x32_bf16(a1_1, b1, A1, 0, 0, 0);        \
        A2 = __builtin_amdgcn_mfma_f32_16x16x32_bf16(a1_2, b1, A2, 0, 0, 0);        \
        A3 = __builtin_amdgcn_mfma_f32_16x16x32_bf16(a1_3, b1, A3, 0, 0, 0);

    // ---- pass 1: per-wave per-token max over its 64 codes ----
    #pragma unroll 1
    for (int g16 = 0; g16 < 16; ++g16) {
        SCORES(g16, c0, c1, c2, c3);
        float mm = fmaxf(fmaxf(fmaxf(c0[0], c0[1]), fmaxf(c0[2], c0[3])),
                         fmaxf(fmaxf(c1[0], c1[1]), fmaxf(c1[2], c1[3])));
        mm = fmaxf(mm, fmaxf(fmaxf(c2[0], c2[1]), fmaxf(c2[2], c2[3])));
        mm = fmaxf(mm, fmaxf(fmaxf(c3[0], c3[1]), fmaxf(c3[2], c3[3])));
        mm = fmaxf(mm, __shfl_xor(mm, 16));
        mm = fmaxf(mm, __shfl_xor(mm, 32));
        if (l < 16) wavemax[wv][g16 * 16 + l] = mm;
    }
    __syncthreads();

    // ---- per-token global max -> threshold ----
    if (tid < 256) {
        float gm = wavemax[0][tid];
        #pragma unroll
        for (int w = 1; w < 8; ++w) gm = fmaxf(gm, wavemax[w][tid]);
        const float xsq = xsqpart[0][tid] + xsqpart[1][tid];
        thrArr[tid] = gm - (ldexpf(sqrtf(xsq * wm2), -7) + 0.02f);  // 2E certified
    }
    __syncthreads();

    // ---- pass 2: candidate masks (bit = local code = j*16 + row) ----
    const int rowbase = (l >> 4) * 4;
    #pragma unroll 1
    for (int g16 = 0; g16 < 16; ++g16) {
        const float thr = thrArr[g16 * 16 + (l & 15)];
        SCORES(g16, c0, c1, c2, c3);
        unsigned long long msk = 0;
        {
            unsigned b4 = 0;
            #pragma unroll
            for (int r = 0; r < 4; ++r) b4 |= (c0[r] >= thr ? 1u : 0u) << r;
            msk |= (unsigned long long)b4 << (0 * 16 + rowbase);
            b4 = 0;
            #pragma unroll
            for (int r = 0; r < 4; ++r) b4 |= (c1[r] >= thr ? 1u : 0u) << r;
            msk |= (unsigned long long)b4 << (1 * 16 + rowbase);
            b4 = 0;
            #pragma unroll
            for (int r = 0; r < 4; ++r) b4 |= (c2[r] >= thr ? 1u : 0u) << r;
            msk |= (unsigned long long)b4 << (2 * 16 + rowbase);
            b4 = 0;
            #pragma unroll
            for (int r = 0; r < 4; ++r) b4 |= (c3[r] >= thr ? 1u : 0u) << r;
            msk |= (unsigned long long)b4 << (3 * 16 + rowbase);
        }
        msk |= __shfl_xor(msk, 16);
        msk |= __shfl_xor(msk, 32);
        if (l < 16) cmask[wv][g16 * 16 + l] = msk;
    }
    #undef SCORES
    __syncthreads();

    // ---- resolution: one thread per token ----
    if (tid < 256) {
        const int tok = tid;
        int cnt = 0;
        #pragma unroll
        for (int w = 0; w < 8; ++w) cnt += __popcll(cmask[w][tok]);
        int bk;
        if (cnt == 1) {                     // certified exact argmin
            bk = 0;
            #pragma unroll
            for (int w = 0; w < 8; ++w) {
                unsigned long long mmm = cmask[w][tok];
                if (mmm) bk = w * 64 + __builtin_ctzll(mmm);
            }
        } else {                            // exact fp64 refine, k ascending
            double bd = 1.0e308;
            int bkm = 0x7fffffff;
            const float* xc = x + (size_t)(b * 64) * HW_ + p0 + tok;
            #pragma unroll
            for (int w = 0; w < 8; ++w) {
                unsigned long long mmm = cmask[w][tok];
                while (mmm) {
                    const int bit = __builtin_ctzll(mmm); mmm &= mmm - 1;
                    const int k = w * 64 + bit;
                    const float* wr = W + k * 64;
                    double p = 0.0;
                    #pragma unroll 1
                    for (int d = 0; d < 64; ++d) {
                        double dl = (double)xc[(size_t)d * HW_] - (double)wr[d];
                        p = fma(dl, dl, p);
                    }
                    if (p < bd) { bd = p; bkm = k; }   // strict <: first index wins
                }
            }
            bk = bkm;
        }
        bkArr[tok] = bk;
    }
    __syncthreads();

    // ---- epilogue: gather W rows (L2-hot), coalesced NCHW store ----
    {
        const int pp = tid & 255;            // token
        const int dh = tid >> 8;             // dim half 0..1
        const int kk = bkArr[pp];
        const float* wr = W + kk * 64 + dh * 32;
        float* ob = out + (size_t)b * 262144 + p0 + pp;
        #pragma unroll
        for (int j = 0; j < 8; ++j) {
            f32x4 v = *(const f32x4*)(wr + j * 4);
            ob[(size_t)(dh * 32 + j * 4 + 0) * HW_] = v[0];
            ob[(size_t)(dh * 32 + j * 4 + 1) * HW_] = v[1];
            ob[(size_t)(dh * 32 + j * 4 + 2) * HW_] = v[2];
            ob[(size_t)(dh * 32 + j * 4 + 3) * HW_] = v[3];
        }
    }
}

extern "C" void kernel_launch(void* const* d_in, const int* in_sizes, int n_in,
                              void* d_out, int out_size, void* d_ws, size_t ws_size,
                              hipStream_t stream) {
    const float* x = (const float*)d_in[0];
    const float* W = (const float*)d_in[1];
    unsigned short* Wb = (unsigned short*)d_ws;              // 64 KiB image
    float* nh = (float*)((char*)d_ws + 65536);               // 512 f32
    int* wmax2i = (int*)((char*)d_ws + 65536 + 2048);        // 1 int (float bits)
    hipMemsetAsync(wmax2i, 0, 4, stream);
    vq_prep<<<512, 64, 0, stream>>>(W, Wb, nh, wmax2i);
    vq_main<<<512, 512, 0, stream>>>(x, W, Wb, nh, wmax2i, (float*)d_out);
}

// Round 14
// 64.629 us; speedup vs baseline: 3.3210x; 3.3210x over previous
//
#include <hip/hip_runtime.h>
#include <stdint.h>

// VectorQuantizer: x[32,64,64,64] NCHW fp32, W[512,64] fp32.
// argmin_k ||x - w_k||^2 ; out = W[argmin] in NCHW.
//
// v14 = v13 with wave-cooperative worklist refine (v13's per-thread serial
// fp64 refine was ~100us of latency-serial chains). Code-slice ownership:
// 512-thr blocks (8 waves), 256 tokens/block; wave w holds A-frags of codes
// w*64..+63 in 32 VGPRs; tokens staged once in swizzled bf16 LDS (2 ds_read
// + 8 MFMA per 16-token group). Margin 2^-7*||x||*Wmax+0.02; singleton
// certified exact; multi tokens -> LDS worklist -> whole-wave fp64 refine.

typedef short short8 __attribute__((ext_vector_type(8)));
typedef float f32x4 __attribute__((ext_vector_type(4)));
typedef unsigned u32x4 __attribute__((ext_vector_type(4)));

#define HW_ 4096

__device__ __forceinline__ unsigned short f2bf(float f) {
    unsigned u = __float_as_uint(f);
    u += 0x7fff + ((u >> 16) & 1);   // RNE to bf16
    return (unsigned short)(u >> 16);
}

// Image: ushort idx(k,d) = (d>>3)*4096 + k*8 + (d&7)   [8 octet-planes]
__global__ __launch_bounds__(64) void vq_prep(const float* __restrict__ W,
                                              unsigned short* __restrict__ Wb,
                                              float* __restrict__ nh,
                                              int* __restrict__ wmax2i) {
    const int k = blockIdx.x, l = threadIdx.x;
    float v = W[k * 64 + l];
    Wb[(l >> 3) * 4096 + k * 8 + (l & 7)] = f2bf(v);
    float s = v * v;
    #pragma unroll
    for (int off = 1; off < 64; off <<= 1) s += __shfl_xor(s, off);
    if (l == 0) {
        nh[k] = -0.5f * s;
        atomicMax(wmax2i, __float_as_int(s));
    }
}

__global__ __launch_bounds__(512, 4) void vq_main(const float* __restrict__ x,
                                                  const float* __restrict__ W,
                                                  const unsigned short* __restrict__ Wb,
                                                  const float* __restrict__ nh,
                                                  const int* __restrict__ wmax2i,
                                                  float* __restrict__ out) {
    __shared__ unsigned short xb[256 * 64];        // 32 KiB swizzled bf16 tokens
    __shared__ float wavemax[8][256];              // 8 KiB
    __shared__ unsigned long long cmask[8][256];   // 16 KiB
    __shared__ float xsqpart[2][256];              // 2 KiB
    __shared__ float thrArr[256];                  // 1 KiB
    __shared__ int bkArr[256];                     // 1 KiB
    __shared__ int wlist[256];                     // 1 KiB worklist
    __shared__ int wcnt;

    const int tid = threadIdx.x;
    const int bid = blockIdx.x;
    const int b = bid >> 4;                 // batch 0..31
    const int p0 = (bid & 15) << 8;         // 256-token spatial base
    const int l = tid & 63;
    const int wv = tid >> 6;                // wave 0..7 owns codes wv*64..+63

    if (tid == 0) wcnt = 0;

    // ---- this wave's A-fragments (4 tiles) + nh C-inits, in registers ----
    short8 a0_0, a0_1, a0_2, a0_3, a1_0, a1_1, a1_2, a1_3;
    f32x4 nhv0, nhv1, nhv2, nhv3;
    {
        const unsigned short* Ap = Wb + (l >> 4) * 4096 + ((wv * 4) * 16 + (l & 15)) * 8;
        const unsigned short* Aq = Ap + 4 * 4096;
        a0_0 = *(const short8*)(Ap);        a1_0 = *(const short8*)(Aq);
        a0_1 = *(const short8*)(Ap + 128);  a1_1 = *(const short8*)(Aq + 128);
        a0_2 = *(const short8*)(Ap + 256);  a1_2 = *(const short8*)(Aq + 256);
        a0_3 = *(const short8*)(Ap + 384);  a1_3 = *(const short8*)(Aq + 384);
        const float* np = nh + (wv * 4) * 16 + (l >> 4) * 4;
        nhv0 = *(const f32x4*)(np);
        nhv1 = *(const f32x4*)(np + 16);
        nhv2 = *(const f32x4*)(np + 32);
        nhv3 = *(const f32x4*)(np + 48);
    }

    // ---- stage 256 tokens into swizzled LDS; xsq partials ----
    {
        const int tok = tid & 255;
        const int half = tid >> 8;
        const float* xp = x + (size_t)(b * 64 + half * 32) * HW_ + p0 + tok;
        float xsq = 0.f;
        #pragma unroll
        for (int c4 = 0; c4 < 4; ++c4) {
            float v[8];
            #pragma unroll
            for (int e = 0; e < 8; ++e) {
                v[e] = xp[(size_t)(c4 * 8 + e) * HW_];
                xsq += v[e] * v[e];
            }
            u32x4 pk;
            #pragma unroll
            for (int q = 0; q < 4; ++q)
                pk[q] = (unsigned)f2bf(v[2 * q]) | ((unsigned)f2bf(v[2 * q + 1]) << 16);
            const int slot = (half * 4 + c4) ^ (tok & 7);
            *(u32x4*)((char*)xb + tok * 128 + slot * 16) = pk;
        }
        xsqpart[half][tok] = xsq;
    }
    const float wm2 = __int_as_float(*wmax2i);
    __syncthreads();

    // lane-constant swizzled byte offsets (tok&7 == l&7 within every group)
    const int off0 = (((l >> 4)    ) ^ (l & 7)) * 16;
    const int off1 = (((l >> 4) + 4) ^ (l & 7)) * 16;
    const char* xbB = (const char*)xb + (l & 15) * 128;

    #define SCORES(G, A0, A1, A2, A3)                                              \
        short8 b0 = *(const short8*)(xbB + (G) * 2048 + off0);                      \
        short8 b1 = *(const short8*)(xbB + (G) * 2048 + off1);                      \
        f32x4 A0 = nhv0, A1 = nhv1, A2 = nhv2, A3 = nhv3;                           \
        A0 = __builtin_amdgcn_mfma_f32_16x16x32_bf16(a0_0, b0, A0, 0, 0, 0);        \
        A1 = __builtin_amdgcn_mfma_f32_16x16x32_bf16(a0_1, b0, A1, 0, 0, 0);        \
        A2 = __builtin_amdgcn_mfma_f32_16x16x32_bf16(a0_2, b0, A2, 0, 0, 0);        \
        A3 = __builtin_amdgcn_mfma_f32_16x16x32_bf16(a0_3, b0, A3, 0, 0, 0);        \
        A0 = __builtin_amdgcn_mfma_f32_16x16x32_bf16(a1_0, b1, A0, 0, 0, 0);        \
        A1 = __builtin_amdgcn_mfma_f32_16x16x32_bf16(a1_1, b1, A1, 0, 0, 0);        \
        A2 = __builtin_amdgcn_mfma_f32_16x16x32_bf16(a1_2, b1, A2, 0, 0, 0);        \
        A3 = __builtin_amdgcn_mfma_f32_16x16x32_bf16(a1_3, b1, A3, 0, 0, 0);

    // ---- pass 1: per-wave per-token max over its 64 codes ----
    #pragma unroll 1
    for (int g16 = 0; g16 < 16; ++g16) {
        SCORES(g16, c0, c1, c2, c3);
        float mm = fmaxf(fmaxf(fmaxf(c0[0], c0[1]), fmaxf(c0[2], c0[3])),
                         fmaxf(fmaxf(c1[0], c1[1]), fmaxf(c1[2], c1[3])));
        mm = fmaxf(mm, fmaxf(fmaxf(c2[0], c2[1]), fmaxf(c2[2], c2[3])));
        mm = fmaxf(mm, fmaxf(fmaxf(c3[0], c3[1]), fmaxf(c3[2], c3[3])));
        mm = fmaxf(mm, __shfl_xor(mm, 16));
        mm = fmaxf(mm, __shfl_xor(mm, 32));
        if (l < 16) wavemax[wv][g16 * 16 + l] = mm;
    }
    __syncthreads();

    // ---- per-token global max -> threshold ----
    if (tid < 256) {
        float gm = wavemax[0][tid];
        #pragma unroll
        for (int w = 1; w < 8; ++w) gm = fmaxf(gm, wavemax[w][tid]);
        const float xsq = xsqpart[0][tid] + xsqpart[1][tid];
        thrArr[tid] = gm - (ldexpf(sqrtf(xsq * wm2), -7) + 0.02f);  // 2E certified
    }
    __syncthreads();

    // ---- pass 2: candidate masks (bit = local code = j*16 + row) ----
    const int rowbase = (l >> 4) * 4;
    #pragma unroll 1
    for (int g16 = 0; g16 < 16; ++g16) {
        const float thr = thrArr[g16 * 16 + (l & 15)];
        SCORES(g16, c0, c1, c2, c3);
        unsigned long long msk = 0;
        {
            unsigned b4 = 0;
            #pragma unroll
            for (int r = 0; r < 4; ++r) b4 |= (c0[r] >= thr ? 1u : 0u) << r;
            msk |= (unsigned long long)b4 << (0 * 16 + rowbase);
            b4 = 0;
            #pragma unroll
            for (int r = 0; r < 4; ++r) b4 |= (c1[r] >= thr ? 1u : 0u) << r;
            msk |= (unsigned long long)b4 << (1 * 16 + rowbase);
            b4 = 0;
            #pragma unroll
            for (int r = 0; r < 4; ++r) b4 |= (c2[r] >= thr ? 1u : 0u) << r;
            msk |= (unsigned long long)b4 << (2 * 16 + rowbase);
            b4 = 0;
            #pragma unroll
            for (int r = 0; r < 4; ++r) b4 |= (c3[r] >= thr ? 1u : 0u) << r;
            msk |= (unsigned long long)b4 << (3 * 16 + rowbase);
        }
        msk |= __shfl_xor(msk, 16);
        msk |= __shfl_xor(msk, 32);
        if (l < 16) cmask[wv][g16 * 16 + l] = msk;
    }
    #undef SCORES
    __syncthreads();

    // ---- resolution: singleton inline; multi -> worklist ----
    if (tid < 256) {
        const int tok = tid;
        int cnt = 0;
        #pragma unroll
        for (int w = 0; w < 8; ++w) cnt += __popcll(cmask[w][tok]);
        if (cnt == 1) {                     // certified exact argmin
            int bk = 0;
            #pragma unroll
            for (int w = 0; w < 8; ++w) {
                unsigned long long mmm = cmask[w][tok];
                if (mmm) bk = w * 64 + __builtin_ctzll(mmm);
            }
            bkArr[tok] = bk;
        } else {
            wlist[atomicAdd(&wcnt, 1)] = tok;
        }
    }
    __syncthreads();

    // ---- wave-cooperative fp64 refine over the worklist ----
    {
        const int nW = wcnt;
        for (int i = wv; i < nW; i += 8) {
            const int tok = wlist[i];
            const double xl = (double)x[(size_t)(b * 64 + l) * HW_ + p0 + tok];
            double bd = 1.0e308;
            int bk = 0;
            #pragma unroll 1
            for (int w = 0; w < 8; ++w) {
                unsigned long long mm = cmask[w][tok];
                while (mm) {
                    const int bit = __builtin_ctzll(mm); mm &= mm - 1;
                    const int k = w * 64 + bit;
                    double dl = xl - (double)W[k * 64 + l];
                    double p = dl * dl;
                    #pragma unroll
                    for (int off = 1; off < 64; off <<= 1) p += __shfl_xor(p, off);
                    if (p < bd) { bd = p; bk = k; }   // ascending k + strict <
                }
            }
            if (l == 0) bkArr[tok] = bk;
        }
    }
    __syncthreads();

    // ---- epilogue: gather W rows (L2-hot), coalesced NCHW store ----
    {
        const int pp = tid & 255;            // token
        const int dh = tid >> 8;             // dim half 0..1
        const int kk = bkArr[pp];
        const float* wr = W + kk * 64 + dh * 32;
        float* ob = out + (size_t)b * 262144 + p0 + pp;
        #pragma unroll
        for (int j = 0; j < 8; ++j) {
            f32x4 v = *(const f32x4*)(wr + j * 4);
            ob[(size_t)(dh * 32 + j * 4 + 0) * HW_] = v[0];
            ob[(size_t)(dh * 32 + j * 4 + 1) * HW_] = v[1];
            ob[(size_t)(dh * 32 + j * 4 + 2) * HW_] = v[2];
            ob[(size_t)(dh * 32 + j * 4 + 3) * HW_] = v[3];
        }
    }
}

extern "C" void kernel_launch(void* const* d_in, const int* in_sizes, int n_in,
                              void* d_out, int out_size, void* d_ws, size_t ws_size,
                              hipStream_t stream) {
    const float* x = (const float*)d_in[0];
    const float* W = (const float*)d_in[1];
    unsigned short* Wb = (unsigned short*)d_ws;              // 64 KiB image
    float* nh = (float*)((char*)d_ws + 65536);               // 512 f32
    int* wmax2i = (int*)((char*)d_ws + 65536 + 2048);        // 1 int (float bits)
    hipMemsetAsync(wmax2i, 0, 4, stream);
    vq_prep<<<512, 64, 0, stream>>>(W, Wb, nh, wmax2i);
    vq_main<<<512, 512, 0, stream>>>(x, W, Wb, nh, wmax2i, (float*)d_out);
}

// Round 15
// 62.301 us; speedup vs baseline: 3.4451x; 1.0374x over previous
//
#include <hip/hip_runtime.h>
#include <stdint.h>

// VectorQuantizer: x[32,64,64,64] NCHW fp32, W[512,64] fp32.
// argmin_k ||x - w_k||^2 ; out = W[argmin] in NCHW.
//
// v15: single-pass sweep + 4 blocks/CU. 512-thr blocks (8 waves), 128
// tokens/block, grid 1024. Wave w holds A-frags of codes w*64..+63 in 32
// VGPRs; tokens staged once in swizzled bf16 LDS. Per iter: 8 MFMA -> wave
// max mm AND candidate mask (>= mm - margin_tok) in one pass. Resolution
// qualifies waves by m_w >= gmax - margin (masks are certified supersets);
// singleton exact, multi -> worklist -> whole-wave fp64 refine.

typedef short short8 __attribute__((ext_vector_type(8)));
typedef float f32x4 __attribute__((ext_vector_type(4)));
typedef unsigned u32x4 __attribute__((ext_vector_type(4)));

#define HW_ 4096

__device__ __forceinline__ unsigned short f2bf(float f) {
    unsigned u = __float_as_uint(f);
    u += 0x7fff + ((u >> 16) & 1);   // RNE to bf16
    return (unsigned short)(u >> 16);
}

// Image: ushort idx(k,d) = (d>>3)*4096 + k*8 + (d&7)   [8 octet-planes]
__global__ __launch_bounds__(64) void vq_prep(const float* __restrict__ W,
                                              unsigned short* __restrict__ Wb,
                                              float* __restrict__ nh,
                                              int* __restrict__ wmax2i) {
    const int k = blockIdx.x, l = threadIdx.x;
    float v = W[k * 64 + l];
    Wb[(l >> 3) * 4096 + k * 8 + (l & 7)] = f2bf(v);
    float s = v * v;
    #pragma unroll
    for (int off = 1; off < 64; off <<= 1) s += __shfl_xor(s, off);
    if (l == 0) {
        nh[k] = -0.5f * s;
        atomicMax(wmax2i, __float_as_int(s));
    }
}

__global__ __launch_bounds__(512, 4) void vq_main(const float* __restrict__ x,
                                                  const float* __restrict__ W,
                                                  const unsigned short* __restrict__ Wb,
                                                  const float* __restrict__ nh,
                                                  const int* __restrict__ wmax2i,
                                                  float* __restrict__ out) {
    __shared__ unsigned short xb[128 * 64];        // 16 KiB swizzled bf16 tokens
    __shared__ float wavemax[8][128];              // 4 KiB
    __shared__ unsigned long long cmask[8][128];   // 8 KiB
    __shared__ float xsqpart[4][128];              // 2 KiB
    __shared__ float marginArr[128];               // 0.5 KiB
    __shared__ float thrArr[128];                  // 0.5 KiB
    __shared__ int bkArr[128];                     // 0.5 KiB
    __shared__ int wlist[128];                     // 0.5 KiB
    __shared__ int wcnt;

    const int tid = threadIdx.x;
    const int bid = blockIdx.x;
    const int b = bid >> 5;                 // batch 0..31
    const int p0 = (bid & 31) << 7;         // 128-token spatial base
    const int l = tid & 63;
    const int wv = tid >> 6;                // wave 0..7 owns codes wv*64..+63

    if (tid == 0) wcnt = 0;

    // ---- this wave's A-fragments (4 tiles) + nh C-inits, in registers ----
    short8 a0_0, a0_1, a0_2, a0_3, a1_0, a1_1, a1_2, a1_3;
    f32x4 nhv0, nhv1, nhv2, nhv3;
    {
        const unsigned short* Ap = Wb + (l >> 4) * 4096 + ((wv * 4) * 16 + (l & 15)) * 8;
        const unsigned short* Aq = Ap + 4 * 4096;
        a0_0 = *(const short8*)(Ap);        a1_0 = *(const short8*)(Aq);
        a0_1 = *(const short8*)(Ap + 128);  a1_1 = *(const short8*)(Aq + 128);
        a0_2 = *(const short8*)(Ap + 256);  a1_2 = *(const short8*)(Aq + 256);
        a0_3 = *(const short8*)(Ap + 384);  a1_3 = *(const short8*)(Aq + 384);
        const float* np = nh + (wv * 4) * 16 + (l >> 4) * 4;
        nhv0 = *(const f32x4*)(np);
        nhv1 = *(const f32x4*)(np + 16);
        nhv2 = *(const f32x4*)(np + 32);
        nhv3 = *(const f32x4*)(np + 48);
    }

    // ---- stage 128 tokens into swizzled LDS; xsq partials ----
    {
        const int tok = tid & 127;
        const int q = tid >> 7;              // dim quarter 0..3
        const float* xp = x + (size_t)(b * 64 + q * 16) * HW_ + p0 + tok;
        float xsq = 0.f;
        float v[16];
        #pragma unroll
        for (int e = 0; e < 16; ++e) {
            v[e] = xp[(size_t)e * HW_];
            xsq += v[e] * v[e];
        }
        u32x4 pk0, pk1;
        #pragma unroll
        for (int p = 0; p < 4; ++p) {
            pk0[p] = (unsigned)f2bf(v[2 * p])     | ((unsigned)f2bf(v[2 * p + 1]) << 16);
            pk1[p] = (unsigned)f2bf(v[8 + 2 * p]) | ((unsigned)f2bf(v[9 + 2 * p]) << 16);
        }
        const int s0 = (q * 2)     ^ (tok & 7);
        const int s1 = (q * 2 + 1) ^ (tok & 7);
        *(u32x4*)((char*)xb + tok * 128 + s0 * 16) = pk0;
        *(u32x4*)((char*)xb + tok * 128 + s1 * 16) = pk1;
        xsqpart[q][tok] = xsq;
    }
    const float wm2 = __int_as_float(*wmax2i);
    __syncthreads();
    if (tid < 128) {
        const float xsq = xsqpart[0][tid] + xsqpart[1][tid] + xsqpart[2][tid] + xsqpart[3][tid];
        marginArr[tid] = ldexpf(sqrtf(xsq * wm2), -7) + 0.02f;   // 2E certified
    }
    __syncthreads();

    // lane-constant swizzled byte offsets (tok&7 == l&7 within every group)
    const int off0 = (((l >> 4)    ) ^ (l & 7)) * 16;
    const int off1 = (((l >> 4) + 4) ^ (l & 7)) * 16;
    const char* xbB = (const char*)xb + (l & 15) * 128;
    const int rowbase = (l >> 4) * 4;

    // ---- single sweep: scores -> wave max + candidate mask per token ----
    #pragma unroll 1
    for (int g16 = 0; g16 < 8; ++g16) {
        const float marg = marginArr[g16 * 16 + (l & 15)];
        short8 b0 = *(const short8*)(xbB + g16 * 2048 + off0);
        short8 b1 = *(const short8*)(xbB + g16 * 2048 + off1);
        f32x4 c0 = nhv0, c1 = nhv1, c2 = nhv2, c3 = nhv3;
        c0 = __builtin_amdgcn_mfma_f32_16x16x32_bf16(a0_0, b0, c0, 0, 0, 0);
        c1 = __builtin_amdgcn_mfma_f32_16x16x32_bf16(a0_1, b0, c1, 0, 0, 0);
        c2 = __builtin_amdgcn_mfma_f32_16x16x32_bf16(a0_2, b0, c2, 0, 0, 0);
        c3 = __builtin_amdgcn_mfma_f32_16x16x32_bf16(a0_3, b0, c3, 0, 0, 0);
        c0 = __builtin_amdgcn_mfma_f32_16x16x32_bf16(a1_0, b1, c0, 0, 0, 0);
        c1 = __builtin_amdgcn_mfma_f32_16x16x32_bf16(a1_1, b1, c1, 0, 0, 0);
        c2 = __builtin_amdgcn_mfma_f32_16x16x32_bf16(a1_2, b1, c2, 0, 0, 0);
        c3 = __builtin_amdgcn_mfma_f32_16x16x32_bf16(a1_3, b1, c3, 0, 0, 0);

        float mm = fmaxf(fmaxf(fmaxf(c0[0], c0[1]), fmaxf(c0[2], c0[3])),
                         fmaxf(fmaxf(c1[0], c1[1]), fmaxf(c1[2], c1[3])));
        mm = fmaxf(mm, fmaxf(fmaxf(c2[0], c2[1]), fmaxf(c2[2], c2[3])));
        mm = fmaxf(mm, fmaxf(fmaxf(c3[0], c3[1]), fmaxf(c3[2], c3[3])));
        mm = fmaxf(mm, __shfl_xor(mm, 16));
        mm = fmaxf(mm, __shfl_xor(mm, 32));
        const float thr = mm - marg;

        unsigned long long msk = 0;
        unsigned b4 = 0;
        #pragma unroll
        for (int r = 0; r < 4; ++r) b4 |= (c0[r] >= thr ? 1u : 0u) << r;
        msk |= (unsigned long long)b4 << (0 * 16 + rowbase);
        b4 = 0;
        #pragma unroll
        for (int r = 0; r < 4; ++r) b4 |= (c1[r] >= thr ? 1u : 0u) << r;
        msk |= (unsigned long long)b4 << (1 * 16 + rowbase);
        b4 = 0;
        #pragma unroll
        for (int r = 0; r < 4; ++r) b4 |= (c2[r] >= thr ? 1u : 0u) << r;
        msk |= (unsigned long long)b4 << (2 * 16 + rowbase);
        b4 = 0;
        #pragma unroll
        for (int r = 0; r < 4; ++r) b4 |= (c3[r] >= thr ? 1u : 0u) << r;
        msk |= (unsigned long long)b4 << (3 * 16 + rowbase);

        msk |= __shfl_xor(msk, 16);
        msk |= __shfl_xor(msk, 32);
        if (l < 16) {
            wavemax[wv][g16 * 16 + l] = mm;
            cmask[wv][g16 * 16 + l] = msk;
        }
    }
    __syncthreads();

    // ---- resolution: qualify waves, singleton inline; multi -> worklist ----
    if (tid < 128) {
        const int tok = tid;
        float gm = wavemax[0][tok];
        #pragma unroll
        for (int w = 1; w < 8; ++w) gm = fmaxf(gm, wavemax[w][tok]);
        const float thr = gm - marginArr[tok];
        thrArr[tok] = thr;
        int cnt = 0;
        int bk = -1;
        #pragma unroll
        for (int w = 0; w < 8; ++w) {
            if (wavemax[w][tok] >= thr) {
                unsigned long long mmm = cmask[w][tok];
                cnt += __popcll(mmm);
                if (mmm) bk = w * 64 + __builtin_ctzll(mmm);
            }
        }
        if (cnt == 1) bkArr[tok] = bk;      // certified exact argmin
        else wlist[atomicAdd(&wcnt, 1)] = tok;
    }
    __syncthreads();

    // ---- wave-cooperative fp64 refine over the worklist ----
    {
        const int nW = wcnt;
        for (int i = wv; i < nW; i += 8) {
            const int tok = wlist[i];
            const float thr = thrArr[tok];
            const double xl = (double)x[(size_t)(b * 64 + l) * HW_ + p0 + tok];
            double bd = 1.0e308;
            int bk = 0x7fffffff;
            #pragma unroll 1
            for (int w = 0; w < 8; ++w) {
                if (wavemax[w][tok] < thr) continue;
                unsigned long long mm = cmask[w][tok];
                while (mm) {
                    const int bit = __builtin_ctzll(mm); mm &= mm - 1;
                    const int k = w * 64 + bit;
                    double dl = xl - (double)W[k * 64 + l];
                    double p = dl * dl;
                    #pragma unroll
                    for (int off = 1; off < 64; off <<= 1) p += __shfl_xor(p, off);
                    if (p < bd) { bd = p; bk = k; }   // ascending k + strict <
                }
            }
            if (l == 0) bkArr[tok] = bk;
        }
    }
    __syncthreads();

    // ---- epilogue: gather W rows (L2-hot), coalesced NCHW store ----
    {
        const int pp = tid & 127;            // token
        const int dq = tid >> 7;             // dim quarter 0..3
        const int kk = bkArr[pp];
        const float* wr = W + kk * 64 + dq * 16;
        float* ob = out + (size_t)b * 262144 + p0 + pp;
        #pragma unroll
        for (int j = 0; j < 4; ++j) {
            f32x4 v = *(const f32x4*)(wr + j * 4);
            ob[(size_t)(dq * 16 + j * 4 + 0) * HW_] = v[0];
            ob[(size_t)(dq * 16 + j * 4 + 1) * HW_] = v[1];
            ob[(size_t)(dq * 16 + j * 4 + 2) * HW_] = v[2];
            ob[(size_t)(dq * 16 + j * 4 + 3) * HW_] = v[3];
        }
    }
}

extern "C" void kernel_launch(void* const* d_in, const int* in_sizes, int n_in,
                              void* d_out, int out_size, void* d_ws, size_t ws_size,
                              hipStream_t stream) {
    const float* x = (const float*)d_in[0];
    const float* W = (const float*)d_in[1];
    unsigned short* Wb = (unsigned short*)d_ws;              // 64 KiB image
    float* nh = (float*)((char*)d_ws + 65536);               // 512 f32
    int* wmax2i = (int*)((char*)d_ws + 65536 + 2048);        // 1 int (float bits)
    hipMemsetAsync(wmax2i, 0, 4, stream);
    vq_prep<<<512, 64, 0, stream>>>(W, Wb, nh, wmax2i);
    vq_main<<<1024, 512, 0, stream>>>(x, W, Wb, nh, wmax2i, (float*)d_out);
}